// Round 3
// baseline (5427.784 us; speedup 1.0000x reference)
//
#include <hip/hip_runtime.h>
#include <cstdint>

typedef _Float16 f16;
typedef _Float16 f16x8 __attribute__((ext_vector_type(8)));
typedef float f32x4 __attribute__((ext_vector_type(4)));
typedef unsigned int u32;

#define DEV __device__ __forceinline__

DEV void gll16(const void* g, void* l) {
  __builtin_amdgcn_global_load_lds((const __attribute__((address_space(1))) u32*)g,
                                   (__attribute__((address_space(3))) u32*)l, 16, 0, 0);
}

DEV float wsum(float v) {
#pragma unroll
  for (int o = 32; o; o >>= 1) v += __shfl_xor(v, o);
  return v;
}

struct MP {
  const int* tok; const float* etab;
  const float* Wq; const float* bq; const float* Wk; const float* bk;
  const float* Wv; const float* bv; const float* Wo; const float* bo;
  const float* ln1g; const float* ln1b; const float* ln2g; const float* ln2b;
  const float* Wfc; const float* bfc; const float* Wpr; const float* bpr;
  const float* rw1; const float* rw2; const float* Wfin; const float* bfin;
  const float* lnfg; const float* lnfb;
  f16* actA; float* rawA; float* rawB; float* rawC; float* rawD; float* ssq;
  f16* qhat; f16* khat; f16* vT; f16* ao; f16* fcact;
  f16* wqkvT; f16* woT; f16* wfcT; f16* wprT; f16* wfinT;
  u32* bar; float* out;
};

// ---- two-level grid barrier (32 per XCD-group lane, 8 groups) ----
DEV void gbar(const MP& p) {
  __syncthreads();
  if (threadIdx.x == 0) {
    u32* c8 = p.bar + (blockIdx.x & 7) * 32;   // 128B apart
    u32* root = p.bar + 256;
    u32* gen = p.bar + 260;
    u32 g = __hip_atomic_load(gen, __ATOMIC_RELAXED, __HIP_MEMORY_SCOPE_AGENT);
    __threadfence();
    u32 a = __hip_atomic_fetch_add(c8, 1u, __ATOMIC_ACQ_REL, __HIP_MEMORY_SCOPE_AGENT);
    if (a == 31u) {
      __hip_atomic_store(c8, 0u, __ATOMIC_RELAXED, __HIP_MEMORY_SCOPE_AGENT);
      u32 b = __hip_atomic_fetch_add(root, 1u, __ATOMIC_ACQ_REL, __HIP_MEMORY_SCOPE_AGENT);
      if (b == 7u) {
        __hip_atomic_store(root, 0u, __ATOMIC_RELAXED, __HIP_MEMORY_SCOPE_AGENT);
        __hip_atomic_store(gen, g + 1u, __ATOMIC_RELEASE, __HIP_MEMORY_SCOPE_AGENT);
      } else {
        for (int it = 0; it < (1 << 22); ++it) {
          if (__hip_atomic_load(gen, __ATOMIC_ACQUIRE, __HIP_MEMORY_SCOPE_AGENT) != g) break;
          __builtin_amdgcn_s_sleep(4);
        }
      }
    } else {
      for (int it = 0; it < (1 << 22); ++it) {
        if (__hip_atomic_load(gen, __ATOMIC_ACQUIRE, __HIP_MEMORY_SCOPE_AGENT) != g) break;
        __builtin_amdgcn_s_sleep(4);
      }
    }
    __threadfence();
  }
  __syncthreads();
}

// ---- 64x64 f32->f16 transpose tile through LDS ----
DEV void trans_tile(const float* W, f16* BT, int K, int N, int ldk, int n0, int k0,
                    char* SM) {
  float* tile = (float*)SM;  // [64][65]
  const int tid = threadIdx.x;
  const int c = tid & 63, r0 = tid >> 6;  // 8 row-groups
#pragma unroll
  for (int i = 0; i < 8; i++) {
    int kr = r0 + i * 8;
    int k = k0 + kr, n = n0 + c;
    tile[kr * 65 + c] = (k < K && n < N) ? W[(size_t)k * N + n] : 0.f;
  }
  __syncthreads();
#pragma unroll
  for (int i = 0; i < 8; i++) {
    int nn = r0 + i * 8;
    BT[(size_t)(n0 + nn) * ldk + k0 + c] = (f16)tile[c * 65 + nn];
  }
  __syncthreads();
}

// ---- 128x128 GEMM task, BK=64, LDS double-buffered, 8 waves (4m x 2n) ----
// EPI0: O[row*520+col+1]=acc  EPI1: QKV->qhat/khat/vT  EPI2: gelu->fcact(H1)+ssq
// EPI3: O partial (+ rank-1 t(ssq)*c0 when addR1)
template <int EPI>
DEV void gemm_task(const f16* A, const f16* B, int lda, int ldb, int tm, int tn,
                   int kbeg, int ksteps, float* O, const float* c0, const float* c1,
                   const float* c2, float* ssq, f16* H1, f16* H2, f16* H3,
                   int addR1, char* SM) {
  const int tid = threadIdx.x, wid = tid >> 6, lane = tid & 63;
  const int l15 = lane & 15, l4 = lane >> 4;
  const int wm = wid & 3, wn = wid >> 2;
  const int m0 = tm * 128, n0 = tn * 128;
  f32x4 acc[2][4];
#pragma unroll
  for (int i = 0; i < 2; i++)
#pragma unroll
    for (int j = 0; j < 4; j++) acc[i][j] = (f32x4){0.f, 0.f, 0.f, 0.f};
  const size_t ldab = (size_t)lda * 2, ldbb = (size_t)ldb * 2;
  const int swz = ((lane & 7) ^ (lane >> 3)) * 16;
  const char* Ab = (const char*)A + (size_t)(m0 + (lane >> 3)) * ldab + swz + (size_t)kbeg * 2;
  const char* Bb = (const char*)B + (size_t)(n0 + (lane >> 3)) * ldbb + swz + (size_t)kbeg * 2;
  auto stage = [&](int buf, int ks) {
    char* da = SM + buf * 32768;
    char* db = da + 16384;
    for (int i = wid; i < 16; i += 8) gll16(Ab + (size_t)(i * 8) * ldab + ks * 128, da + i * 1024);
    for (int i = wid; i < 16; i += 8) gll16(Bb + (size_t)(i * 8) * ldbb + ks * 128, db + i * 1024);
  };
  stage(0, 0);
  __syncthreads();
  int cur = 0;
  for (int ks = 0; ks < ksteps; ks++) {
    if (ks + 1 < ksteps) stage(cur ^ 1, ks + 1);
    const f16* sA = (const f16*)(SM + cur * 32768);
    const f16* sB = (const f16*)(SM + cur * 32768 + 16384);
#pragma unroll
    for (int kk = 0; kk < 2; kk++) {
      f16x8 af[2], bf[4];
#pragma unroll
      for (int i = 0; i < 2; i++) {
        int row = wm * 32 + i * 16 + l15;
        af[i] = *(const f16x8*)(sA + row * 64 + (((kk * 4 + l4) ^ (l15 & 7)) * 8));
      }
#pragma unroll
      for (int j = 0; j < 4; j++) {
        int row = wn * 64 + j * 16 + l15;
        bf[j] = *(const f16x8*)(sB + row * 64 + (((kk * 4 + l4) ^ (l15 & 7)) * 8));
      }
#pragma unroll
      for (int i = 0; i < 2; i++)
#pragma unroll
        for (int j = 0; j < 4; j++)
          acc[i][j] = __builtin_amdgcn_mfma_f32_16x16x32_f16(af[i], bf[j], acc[i][j], 0, 0, 0);
    }
    __syncthreads();
    cur ^= 1;
  }
  if (EPI == 0) {
#pragma unroll
    for (int i = 0; i < 2; i++) {
      int row = m0 + wm * 32 + i * 16 + l4 * 4;
#pragma unroll
      for (int j = 0; j < 4; j++) {
        int col = n0 + wn * 64 + j * 16 + l15;
#pragma unroll
        for (int r = 0; r < 4; r++) O[(size_t)(row + r) * 520 + col + 1] = acc[i][j][r];
      }
    }
  } else if (EPI == 1) {
    const int cb = (n0 >> 6) + wn;
    const int typ = cb >> 3, h = cb & 7;
    const float* bb = (typ == 0) ? c0 : (typ == 1) ? c1 : c2;
    float bj[4];
#pragma unroll
    for (int j = 0; j < 4; j++) bj[j] = bb[h * 64 + j * 16 + l15];
    const float qs = (typ == 0) ? 0.25f : 1.0f;
#pragma unroll
    for (int i = 0; i < 2; i++) {
#pragma unroll
      for (int r = 0; r < 4; r++) {
        float y[4], ss = 0.f;
#pragma unroll
        for (int j = 0; j < 4; j++) { y[j] = acc[i][j][r] + bj[j]; ss += y[j] * y[j]; }
        ss += __shfl_xor(ss, 1); ss += __shfl_xor(ss, 2);
        ss += __shfl_xor(ss, 4); ss += __shfl_xor(ss, 8);
        float t = sqrtf(ss + 1.f);
        int row = m0 + wm * 32 + i * 16 + l4 * 4 + r;
        int b = row >> 10, s = row & 1023, bh = b * 8 + h;
        if (typ < 2) {
          f16* dst = typ ? H2 : H1;
          size_t base = ((size_t)bh * 1024 + s) * 88;
#pragma unroll
          for (int j = 0; j < 4; j++) dst[base + j * 16 + l15] = (f16)(qs * y[j]);
          if (l15 == 0) dst[base + 64] = (f16)(qs * t);
        } else {
#pragma unroll
          for (int j = 0; j < 4; j++)
            H3[((size_t)bh * 80 + j * 16 + l15) * 1024 + s] = (f16)y[j];
          if (l15 == 0) H3[((size_t)bh * 80 + 64) * 1024 + s] = (f16)t;
        }
      }
    }
  } else if (EPI == 2) {
#pragma unroll
    for (int i = 0; i < 2; i++) {
#pragma unroll
      for (int r = 0; r < 4; r++) {
        int row = m0 + wm * 32 + i * 16 + l4 * 4 + r;
        float ss = 0.f;
#pragma unroll
        for (int j = 0; j < 4; j++) {
          int col = n0 + wn * 64 + j * 16 + l15;
          float gg = 0.f;
          if (col < 2047) {
            float yv = acc[i][j][r] + c0[col];
            float z = 0.7978845608f * (yv + 0.044715f * yv * yv * yv);
            float th = 1.f - 2.f / (__expf(2.f * z) + 1.f);
            gg = 0.5f * yv * (1.f + th);
          }
          ss += gg * gg;
          H1[(size_t)row * 2048 + col] = (f16)gg;
        }
        ss += __shfl_xor(ss, 1); ss += __shfl_xor(ss, 2);
        ss += __shfl_xor(ss, 4); ss += __shfl_xor(ss, 8);
        if (l15 == 0) atomicAdd(ssq + row, ss);
      }
    }
  } else {
#pragma unroll
    for (int i = 0; i < 2; i++) {
#pragma unroll
      for (int r = 0; r < 4; r++) {
        int row = m0 + wm * 32 + i * 16 + l4 * 4 + r;
        float t = addR1 ? sqrtf(ssq[row] + 1.f) : 0.f;
#pragma unroll
        for (int j = 0; j < 4; j++) {
          int col = n0 + wn * 64 + j * 16 + l15;
          float v = acc[i][j][r];
          if (addR1) v += t * ((col < 511) ? c0[col] : 0.f);
          O[(size_t)row * 520 + col + 1] = v;
        }
      }
    }
  }
}

// ---- per-wave flash attention + l_project ----
DEV void attn_task(int t, const f16* qhat, const f16* khat, const f16* vT, f16* ao,
                   char* sPb) {
  const int lane = threadIdx.x & 63;
  const int bh = t & 15, rt = 63 - (t >> 4);
  const int l15 = lane & 15, l4 = lane >> 4;
  f16* sP = (f16*)sPb;
  const f16* qp = qhat + ((size_t)bh * 1024 + rt * 16) * 88;
  const f16* kp = khat + (size_t)bh * 1024 * 88;
  const f16* vp = vT + (size_t)bh * 80 * 1024;
  f16x8 qf0 = *(const f16x8*)(qp + l15 * 88 + l4 * 8);
  f16x8 qf1 = *(const f16x8*)(qp + l15 * 88 + 32 + l4 * 8);
  float qth[4];
#pragma unroll
  for (int r = 0; r < 4; r++) qth[r] = (float)qp[(l4 * 4 + r) * 88 + 64];
  f32x4 acc[5];
#pragma unroll
  for (int i = 0; i < 5; i++) acc[i] = (f32x4){0, 0, 0, 0};
  float mrun[4] = {-3e38f, -3e38f, -3e38f, -3e38f}, lrun[4] = {0, 0, 0, 0};
  const int nt = (rt >> 2) + 1;
  for (int jt = 0; jt < nt; ++jt) {
    const int j0 = jt * 64;
    const bool dt = (jt == nt - 1);
    f32x4 sc[4];
#pragma unroll
    for (int fn = 0; fn < 4; fn++) {
      const f16* kb = kp + (size_t)(j0 + fn * 16 + l15) * 88;
      f16x8 k0v = *(const f16x8*)(kb + l4 * 8);
      f16x8 k1v = *(const f16x8*)(kb + 32 + l4 * 8);
      f32x4 a = (f32x4){0, 0, 0, 0};
      a = __builtin_amdgcn_mfma_f32_16x16x32_f16(qf0, k0v, a, 0, 0, 0);
      a = __builtin_amdgcn_mfma_f32_16x16x32_f16(qf1, k1v, a, 0, 0, 0);
      sc[fn] = a;
    }
    float s[4][4];
#pragma unroll
    for (int fn = 0; fn < 4; fn++) {
      float ktc = (float)kp[(size_t)(j0 + fn * 16 + l15) * 88 + 64];
      int col = j0 + fn * 16 + l15;
#pragma unroll
      for (int r = 0; r < 4; r++) {
        int row = rt * 16 + l4 * 4 + r;
        float v = sc[fn][r] - qth[r] * ktc;
        s[fn][r] = (!dt || col <= row) ? v : -3e38f;
      }
    }
    float mnew[4], al[4], rs[4];
#pragma unroll
    for (int r = 0; r < 4; r++) {
      float tm = fmaxf(fmaxf(s[0][r], s[1][r]), fmaxf(s[2][r], s[3][r]));
#pragma unroll
      for (int o = 8; o; o >>= 1) tm = fmaxf(tm, __shfl_xor(tm, o));
      mnew[r] = fmaxf(mrun[r], tm);
      al[r] = exp2f((mrun[r] - mnew[r]) * 1.44269504f);
      mrun[r] = mnew[r];
      rs[r] = 0.f;
    }
#pragma unroll
    for (int fn = 0; fn < 4; fn++)
#pragma unroll
      for (int r = 0; r < 4; r++) {
        float pv = exp2f((s[fn][r] - mnew[r]) * 1.44269504f);
        rs[r] += pv;
        sP[(l4 * 4 + r) * 88 + fn * 16 + l15] = (f16)pv;
      }
#pragma unroll
    for (int r = 0; r < 4; r++) {
#pragma unroll
      for (int o = 8; o; o >>= 1) rs[r] += __shfl_xor(rs[r], o);
      lrun[r] = lrun[r] * al[r] + rs[r];
    }
#pragma unroll
    for (int fd = 0; fd < 5; fd++)
#pragma unroll
      for (int r = 0; r < 4; r++) acc[fd][r] *= al[r];
    asm volatile("s_waitcnt lgkmcnt(0)" ::: "memory");
    __builtin_amdgcn_sched_barrier(0);
#pragma unroll
    for (int ks = 0; ks < 2; ks++) {
      f16x8 pf = *(const f16x8*)(sP + l15 * 88 + ks * 32 + l4 * 8);
#pragma unroll
      for (int fd = 0; fd < 5; fd++) {
        f16x8 vf = *(const f16x8*)(vp + (size_t)(fd * 16 + l15) * 1024 + j0 + ks * 32 + l4 * 8);
        acc[fd] = __builtin_amdgcn_mfma_f32_16x16x32_f16(pf, vf, acc[fd], 0, 0, 0);
      }
    }
  }
  const int b = bh >> 3, h = bh & 7;
#pragma unroll
  for (int r = 0; r < 4; r++) {
    float invl = 1.0f / lrun[r];
    float ss = 0.f, ov[4];
#pragma unroll
    for (int fd = 0; fd < 4; fd++) { ov[fd] = acc[fd][r] * invl; ss += ov[fd] * ov[fd]; }
#pragma unroll
    for (int o = 8; o; o >>= 1) ss += __shfl_xor(ss, o);
    float tv = acc[4][r] * invl;
    tv = __shfl(tv, lane & 48);
    float scp = rsqrtf(fmaxf(tv * tv - ss, 1e-6f));
    int row = rt * 16 + l4 * 4 + r;
    size_t rb = ((size_t)b * 1024 + row) * 640 + h * 65;
    if (l15 == 0) ao[rb] = (f16)(tv * scp);
#pragma unroll
    for (int fd = 0; fd < 4; fd++) ao[rb + 1 + fd * 16 + l15] = (f16)(ov[fd] * scp);
  }
}

// ---- per-wave residual + l_project (+ optional LN) ----
DEV void resproj_row(float (&xreg)[8], int row, const float* rA, const float* rB,
                     const float* rC, const float* rD, int np, const float* bias,
                     float rw, const float* g, const float* bsh, f16* act, int applyLN,
                     float* ssq) {
  const int lane = threadIdx.x & 63, cbase = lane * 8;
  const size_t rb = (size_t)row * 520 + cbase;
  float y[8];
  {
    f32x4 a0 = *(const f32x4*)(rA + rb), a1 = *(const f32x4*)(rA + rb + 4);
    f32x4 b0 = *(const f32x4*)(rB + rb), b1 = *(const f32x4*)(rB + rb + 4);
#pragma unroll
    for (int j = 0; j < 4; j++) { y[j] = a0[j] + b0[j]; y[4 + j] = a1[j] + b1[j]; }
    if (np == 4) {
      f32x4 c0v = *(const f32x4*)(rC + rb), c1v = *(const f32x4*)(rC + rb + 4);
      f32x4 d0 = *(const f32x4*)(rD + rb), d1 = *(const f32x4*)(rD + rb + 4);
#pragma unroll
      for (int j = 0; j < 4; j++) { y[j] += c0v[j] + d0[j]; y[4 + j] += c1v[j] + d1[j]; }
    }
  }
#pragma unroll
  for (int j = 0; j < 8; j++) {
    int c = cbase + j;
    y[j] = (c >= 1) ? (y[j] + bias[c - 1]) : 0.f;
  }
  float lss = 0.f;
#pragma unroll
  for (int j = 0; j < 8; j++) lss += y[j] * y[j];
  float tax = sqrtf(wsum(lss) + 1.f);
  float u[8];
#pragma unroll
  for (int j = 0; j < 8; j++) u[j] = xreg[j] + rw * y[j];
  if (lane == 0) u[0] = xreg[0] + rw * tax;
  float lsu = 0.f, lsu2 = 0.f;
#pragma unroll
  for (int j = 0; j < 8; j++) { lsu += u[j]; lsu2 += u[j] * u[j]; }
  if (lane == 0) { lsu -= u[0]; lsu2 -= u[0] * u[0]; }
  float su = wsum(lsu), su2 = wsum(lsu2);
  float ut = __shfl(u[0], 0);
  float scp = rsqrtf(fmaxf(ut * ut - su2, 1e-6f));
  float nx[8];
#pragma unroll
  for (int j = 0; j < 8; j++) { nx[j] = u[j] * scp; xreg[j] = nx[j]; }
  if (lane == 0) ssq[row] = 0.f;
  f16* ar = act + (size_t)row * 512;
  f16x8 ov;
  if (applyLN) {
    float mu = su * scp * (1.f / 511.f);
    float var = su2 * scp * scp * (1.f / 511.f) - mu * mu;
    float inv = rsqrtf(var + 1e-5f);
    float n[8], lsn = 0.f;
#pragma unroll
    for (int j = 0; j < 8; j++) {
      int c = cbase + j;
      float nv = (c >= 1) ? ((nx[j] - mu) * inv * g[c - 1] + bsh[c - 1]) : 0.f;
      n[j] = nv; lsn += nv * nv;
    }
    float t2 = sqrtf(wsum(lsn) + 1.f);
    if (lane == 0) n[0] = t2;
#pragma unroll
    for (int j = 0; j < 8; j++) ov[j] = (f16)n[j];
  } else {
#pragma unroll
    for (int j = 0; j < 8; j++) ov[j] = (f16)nx[j];
  }
  *(f16x8*)(ar + cbase) = ov;
}

DEV void embed_row(float (&xreg)[8], int row, const int* tok, const float* tbl,
                   const float* g, const float* bsh, f16* act, float* ssq) {
  const int lane = threadIdx.x & 63, cbase = lane * 8;
  const float* e = tbl + (size_t)tok[row] * 511;
  float ev[8];
#pragma unroll
  for (int j = 0; j < 8; j++) {
    int c = cbase + j;
    ev[j] = (c >= 1) ? e[c - 1] : 0.f;
  }
  float lss = 0.f, lsu = 0.f;
#pragma unroll
  for (int j = 0; j < 8; j++) { lss += ev[j] * ev[j]; lsu += ev[j]; }
  float ss = wsum(lss), su = wsum(lsu);
  float t = sqrtf(ss + 1.f);
#pragma unroll
  for (int j = 0; j < 8; j++) xreg[j] = ev[j];
  if (lane == 0) xreg[0] = t;
  float mu = su * (1.f / 511.f);
  float var = ss * (1.f / 511.f) - mu * mu;
  float inv = rsqrtf(var + 1e-5f);
  float n[8], lsn = 0.f;
#pragma unroll
  for (int j = 0; j < 8; j++) {
    int c = cbase + j;
    float nv = (c >= 1) ? ((ev[j] - mu) * inv * g[c - 1] + bsh[c - 1]) : 0.f;
    n[j] = nv; lsn += nv * nv;
  }
  float t2 = sqrtf(wsum(lsn) + 1.f);
  if (lane == 0) n[0] = t2;
  f16x8 ov;
#pragma unroll
  for (int j = 0; j < 8; j++) ov[j] = (f16)n[j];
  *(f16x8*)(act + (size_t)row * 512 + cbase) = ov;
  if (lane == 0) ssq[row] = 0.f;
}

DEV void final_row(int row, const float* raw, const float* bias, const float* g,
                   const float* bsh, float* out) {
  const int lane = threadIdx.x & 63, cbase = lane * 8;
  const size_t rb = (size_t)row * 520 + cbase;
  f32x4 a0 = *(const f32x4*)(raw + rb), a1 = *(const f32x4*)(raw + rb + 4);
  float y[8];
#pragma unroll
  for (int j = 0; j < 4; j++) { y[j] = a0[j]; y[4 + j] = a1[j]; }
  float lss = 0.f, lsu = 0.f;
#pragma unroll
  for (int j = 0; j < 8; j++) {
    int c = cbase + j;
    y[j] = (c >= 1) ? (y[j] + bias[c - 1]) : 0.f;
    lss += y[j] * y[j]; lsu += y[j];
  }
  float s2 = wsum(lss), su = wsum(lsu);
  float mu = su * (1.f / 511.f);
  float var = s2 * (1.f / 511.f) - mu * mu;
  float inv = rsqrtf(var + 1e-5f);
  float n[8], lsn = 0.f;
#pragma unroll
  for (int j = 0; j < 8; j++) {
    int c = cbase + j;
    float nv = (c >= 1) ? ((y[j] - mu) * inv * g[c - 1] + bsh[c - 1]) : 0.f;
    n[j] = nv; lsn += nv * nv;
  }
  float t2 = sqrtf(wsum(lsn) + 1.f);
  if (lane == 0) n[0] = t2;
  float* orow = out + (size_t)row * 512 + cbase;
  f32x4 o0, o1;
#pragma unroll
  for (int j = 0; j < 4; j++) { o0[j] = n[j]; o1[j] = n[4 + j]; }
  *(f32x4*)orow = o0;
  *(f32x4*)(orow + 4) = o1;
}

__global__ __launch_bounds__(512, 2) void k_mega(MP p) {
  const int wg = blockIdx.x, tid = threadIdx.x, wid = tid >> 6;
  __shared__ __align__(16) char SM[65536];
  float xreg[8];
  const int myrow = wg * 8 + wid;

  // ---- phase 0: weight transposes + pad-zero + embed ----
  for (int t = wg; t < 9472; t += 256) {
    const float* W; f16* D; int K, N, ldk, n0, k0;
    if (t < 2304) {
      int mat = t >> 6, tile = t & 63;
      int layer = mat / 3, typ = mat % 3;
      W = (typ == 0 ? p.Wq : typ == 1 ? p.Wk : p.Wv) + (size_t)layer * 262144;
      D = p.wqkvT + (size_t)layer * 786432 + (size_t)typ * 262144;
      K = 512; N = 512; ldk = 512; n0 = (tile >> 3) * 64; k0 = (tile & 7) * 64;
    } else if (t < 3264) {
      int id = t - 2304; int l = id / 80, tile = id % 80;
      W = p.Wo + (size_t)l * 265720; D = p.woT + (size_t)l * 327680;
      K = 520; N = 511; ldk = 640; n0 = (tile / 10) * 64; k0 = (tile % 10) * 64;
    } else if (t < 6336) {
      int id = t - 3264; int l = id >> 8, tile = id & 255;
      W = p.Wfc + (size_t)l * 1048064; D = p.wfcT + (size_t)l * 1048576;
      K = 512; N = 2047; ldk = 512; n0 = (tile >> 3) * 64; k0 = (tile & 7) * 64;
    } else if (t < 9408) {
      int id = t - 6336; int l = id >> 8, tile = id & 255;
      W = p.Wpr + (size_t)l * 1046528 + 511; D = p.wprT + (size_t)l * 1048576;
      K = 2047; N = 511; ldk = 2048; n0 = (tile >> 5) * 64; k0 = (tile & 31) * 64;
    } else {
      int id = t - 9408;
      W = p.Wfin; D = p.wfinT; K = 512; N = 511; ldk = 512;
      n0 = (id >> 3) * 64; k0 = (id & 7) * 64;
    }
    trans_tile(W, D, K, N, ldk, n0, k0, SM);
  }
  for (int i = wg * 512 + tid; i < 2048 * 120; i += 256 * 512)
    p.ao[(size_t)(i / 120) * 640 + 520 + (i % 120)] = (f16)0.f;
  embed_row(xreg, myrow, p.tok, p.etab, p.ln1g, p.ln1b, p.actA, p.ssq);
  gbar(p);

  for (int li = 0; li < 12; li++) {
    const f16* wqkvT_l = p.wqkvT + (size_t)li * 786432;
    const f16* woT_l = p.woT + (size_t)li * 327680;
    const f16* wfcT_l = p.wfcT + (size_t)li * 1048576;
    const f16* wprT_l = p.wprT + (size_t)li * 1048576;
    const float* bq_l = p.bq + li * 512;
    const float* bk_l = p.bk + li * 512;
    const float* bv_l = p.bv + li * 512;
    const float* bo_l = p.bo + li * 511;
    const float* bfc_l = p.bfc + li * 2047;
    const float* bpr_l = p.bpr + li * 511;
    const float* w0_l = p.Wpr + (size_t)li * 1046528;

    for (int t = wg; t < 192; t += 256)
      gemm_task<1>(p.actA, wqkvT_l, 512, 512, t / 12, t % 12, 0, 8, nullptr,
                   bq_l, bk_l, bv_l, nullptr, p.qhat, p.khat, p.vT, 0, SM);
    gbar(p);
    if (wid < 4) attn_task(wid * 256 + wg, p.qhat, p.khat, p.vT, p.ao, SM + wid * 2816);
    gbar(p);
    for (int t = wg; t < 128; t += 256) {
      int tm = t >> 3, tn = (t >> 1) & 3, tz = t & 1;
      gemm_task<0>(p.ao, woT_l, 640, 640, tm, tn, tz * 320, 5,
                   tz ? p.rawB : p.rawA, nullptr, nullptr, nullptr, nullptr,
                   nullptr, nullptr, nullptr, 0, SM);
    }
    gbar(p);
    resproj_row(xreg, myrow, p.rawA, p.rawB, nullptr, nullptr, 2, bo_l, p.rw1[li],
                p.ln2g + li * 511, p.ln2b + li * 511, p.actA, 1, p.ssq);
    gbar(p);
    for (int t = wg; t < 256; t += 256)
      gemm_task<2>(p.actA, wfcT_l, 512, 512, t >> 4, t & 15, 0, 8, nullptr,
                   bfc_l, nullptr, nullptr, p.ssq, p.fcact, nullptr, nullptr, 0, SM);
    gbar(p);
    for (int t = wg; t < 256; t += 256) {
      int tm = t >> 4, tn = (t >> 2) & 3, tz = t & 3;
      float* O = tz == 0 ? p.rawA : tz == 1 ? p.rawB : tz == 2 ? p.rawC : p.rawD;
      gemm_task<3>(p.fcact, wprT_l, 2048, 2048, tm, tn, tz * 512, 8, O,
                   w0_l, nullptr, nullptr, p.ssq, nullptr, nullptr, nullptr, tz == 0, SM);
    }
    gbar(p);
    const float* ng = (li < 11) ? p.ln1g + (li + 1) * 511 : p.ln1g;
    const float* nb = (li < 11) ? p.ln1b + (li + 1) * 511 : p.ln1b;
    resproj_row(xreg, myrow, p.rawA, p.rawB, p.rawC, p.rawD, 4, bpr_l, p.rw2[li],
                ng, nb, p.actA, (li < 11) ? 1 : 0, p.ssq);
    gbar(p);
  }

  for (int t = wg; t < 64; t += 256)
    gemm_task<0>(p.actA, p.wfinT, 512, 512, t >> 2, t & 3, 0, 8, p.rawA,
                 nullptr, nullptr, nullptr, nullptr, nullptr, nullptr, nullptr, 0, SM);
  gbar(p);
  final_row(myrow, p.rawA, p.bfin, p.lnfg, p.lnfb, p.out);
}

extern "C" void kernel_launch(void* const* d_in, const int* in_sizes, int n_in,
                              void* d_out, int out_size, void* d_ws, size_t ws_size,
                              hipStream_t stream) {
  (void)in_sizes; (void)n_in; (void)out_size; (void)ws_size;
  MP p;
  p.tok = (const int*)d_in[0];
  p.etab = (const float*)d_in[1];
  p.Wq = (const float*)d_in[2];  p.bq = (const float*)d_in[3];
  p.Wk = (const float*)d_in[4];  p.bk = (const float*)d_in[5];
  p.Wv = (const float*)d_in[6];  p.bv = (const float*)d_in[7];
  p.Wo = (const float*)d_in[8];  p.bo = (const float*)d_in[9];
  p.ln1g = (const float*)d_in[10]; p.ln1b = (const float*)d_in[11];
  p.ln2g = (const float*)d_in[12]; p.ln2b = (const float*)d_in[13];
  p.Wfc = (const float*)d_in[14]; p.bfc = (const float*)d_in[15];
  p.Wpr = (const float*)d_in[16]; p.bpr = (const float*)d_in[17];
  p.rw1 = (const float*)d_in[18]; p.rw2 = (const float*)d_in[19];
  p.Wfin = (const float*)d_in[20]; p.bfin = (const float*)d_in[21];
  p.lnfg = (const float*)d_in[22]; p.lnfb = (const float*)d_in[23];

  char* wsb = (char*)d_ws;
  size_t off = 0;
  auto alloc = [&](size_t bytes) -> char* {
    char* q = wsb + off;
    off = (off + bytes + 1023) & ~(size_t)1023;
    return q;
  };
  p.actA = (f16*)alloc(2048ull * 512 * 2);
  p.rawA = (float*)alloc(2048ull * 520 * 4);
  p.rawB = (float*)alloc(2048ull * 520 * 4);
  p.rawC = (float*)alloc(2048ull * 520 * 4);
  p.rawD = (float*)alloc(2048ull * 520 * 4);
  p.ssq = (float*)alloc(2048ull * 4);
  p.qhat = (f16*)alloc(16ull * 1024 * 88 * 2);
  p.khat = (f16*)alloc(16ull * 1024 * 88 * 2);
  p.vT = (f16*)alloc(16ull * 80 * 1024 * 2);
  p.ao = (f16*)alloc(2048ull * 640 * 2);
  p.fcact = (f16*)alloc(2048ull * 2048 * 2);
  p.wqkvT = (f16*)alloc(12ull * 786432 * 2);
  p.woT = (f16*)alloc(12ull * 327680 * 2);
  p.wfcT = (f16*)alloc(12ull * 1048576 * 2);
  p.wprT = (f16*)alloc(12ull * 1048576 * 2);
  p.wfinT = (f16*)alloc(512ull * 512 * 2);
  p.bar = (u32*)alloc(4096);
  p.out = (float*)d_out;

  hipMemsetAsync(p.bar, 0, 4096, stream);
  k_mega<<<256, 512, 0, stream>>>(p);
}

// Round 4
// 2523.739 us; speedup vs baseline: 2.1507x; 2.1507x over previous
//
#include <hip/hip_runtime.h>
#include <cstdint>

typedef _Float16 f16;
typedef _Float16 f16x8 __attribute__((ext_vector_type(8)));
typedef float f32x4 __attribute__((ext_vector_type(4)));
typedef unsigned int u32;

#define DEV __device__ __forceinline__

DEV void gll16(const void* g, void* l) {
  __builtin_amdgcn_global_load_lds((const __attribute__((address_space(1))) u32*)g,
                                   (__attribute__((address_space(3))) u32*)l, 16, 0, 0);
}

DEV float wsum(float v) {
#pragma unroll
  for (int o = 32; o; o >>= 1) v += __shfl_xor(v, o);
  return v;
}

struct MP {
  const int* tok; const float* etab;
  const float* Wq; const float* bq; const float* Wk; const float* bk;
  const float* Wv; const float* bv; const float* Wo; const float* bo;
  const float* ln1g; const float* ln1b; const float* ln2g; const float* ln2b;
  const float* Wfc; const float* bfc; const float* Wpr; const float* bpr;
  const float* rw1; const float* rw2; const float* Wfin; const float* bfin;
  const float* lnfg; const float* lnfb;
  f16* actA; float* rawA; float* rawB; float* rawC; float* rawD; float* ssq;
  f16* qhat; f16* khat; f16* vT; f16* ao; f16* fcact;
  f16* wqkvT; f16* woT; f16* wfcT; f16* wprT; f16* wfinT;
  u32* bar; float* out;
};

// ---- two-level grid barrier, monotonic counters, relaxed spin ----
// Arrival: 1 release fence (wbl2) + relaxed RMW tree. Root flips gen with a
// RELEASE store. Waiters spin on RELAXED agent loads (L2-bypassing, NO
// per-iteration invalidate — R3's acquire-spin was invalidating L2
// continuously), then 1 acquire fence (inv) once.
DEV void gbar(const MP& p) {
  __syncthreads();
  if (threadIdx.x == 0) {
    u32* c8 = p.bar + (blockIdx.x & 7) * 32;   // 8 counters, 128B apart
    u32* root = p.bar + 256;
    u32* gen = p.bar + 260;
    u32 g = __hip_atomic_load(gen, __ATOMIC_RELAXED, __HIP_MEMORY_SCOPE_AGENT);
    __builtin_amdgcn_fence(__ATOMIC_RELEASE, "agent");
    u32 a = __hip_atomic_fetch_add(c8, 1u, __ATOMIC_RELAXED, __HIP_MEMORY_SCOPE_AGENT);
    bool flipped = false;
    if ((a & 31u) == 31u) {
      u32 b = __hip_atomic_fetch_add(root, 1u, __ATOMIC_RELAXED, __HIP_MEMORY_SCOPE_AGENT);
      if ((b & 7u) == 7u) {
        __hip_atomic_store(gen, g + 1u, __ATOMIC_RELEASE, __HIP_MEMORY_SCOPE_AGENT);
        flipped = true;
      }
    }
    if (!flipped) {
      for (int it = 0; it < (1 << 22); ++it) {
        if (__hip_atomic_load(gen, __ATOMIC_RELAXED, __HIP_MEMORY_SCOPE_AGENT) != g) break;
        __builtin_amdgcn_s_sleep(2);
      }
    }
    __builtin_amdgcn_fence(__ATOMIC_ACQUIRE, "agent");
  }
  __syncthreads();
}

// ---- 64x64 f32->f16 transpose tile through LDS ----
DEV void trans_tile(const float* W, f16* BT, int K, int N, int ldk, int n0, int k0,
                    char* SM) {
  float* tile = (float*)SM;  // [64][65]
  const int tid = threadIdx.x;
  const int c = tid & 63, r0 = tid >> 6;  // 8 row-groups
#pragma unroll
  for (int i = 0; i < 8; i++) {
    int kr = r0 + i * 8;
    int k = k0 + kr, n = n0 + c;
    tile[kr * 65 + c] = (k < K && n < N) ? W[(size_t)k * N + n] : 0.f;
  }
  __syncthreads();
#pragma unroll
  for (int i = 0; i < 8; i++) {
    int nn = r0 + i * 8;
    BT[(size_t)(n0 + nn) * ldk + k0 + c] = (f16)tile[c * 65 + nn];
  }
  __syncthreads();
}

// ---- 128x128 GEMM task, BK=64, LDS double-buffered, 8 waves (4m x 2n) ----
template <int EPI>
DEV void gemm_task(const f16* A, const f16* B, int lda, int ldb, int tm, int tn,
                   int kbeg, int ksteps, float* O, const float* c0, const float* c1,
                   const float* c2, float* ssq, f16* H1, f16* H2, f16* H3,
                   int addR1, char* SM) {
  const int tid = threadIdx.x, wid = tid >> 6, lane = tid & 63;
  const int l15 = lane & 15, l4 = lane >> 4;
  const int wm = wid & 3, wn = wid >> 2;
  const int m0 = tm * 128, n0 = tn * 128;
  f32x4 acc[2][4];
#pragma unroll
  for (int i = 0; i < 2; i++)
#pragma unroll
    for (int j = 0; j < 4; j++) acc[i][j] = (f32x4){0.f, 0.f, 0.f, 0.f};
  const size_t ldab = (size_t)lda * 2, ldbb = (size_t)ldb * 2;
  const int swz = ((lane & 7) ^ (lane >> 3)) * 16;
  const char* Ab = (const char*)A + (size_t)(m0 + (lane >> 3)) * ldab + swz + (size_t)kbeg * 2;
  const char* Bb = (const char*)B + (size_t)(n0 + (lane >> 3)) * ldbb + swz + (size_t)kbeg * 2;
  auto stage = [&](int buf, int ks) {
    char* da = SM + buf * 32768;
    char* db = da + 16384;
    for (int i = wid; i < 16; i += 8) gll16(Ab + (size_t)(i * 8) * ldab + ks * 128, da + i * 1024);
    for (int i = wid; i < 16; i += 8) gll16(Bb + (size_t)(i * 8) * ldbb + ks * 128, db + i * 1024);
  };
  stage(0, 0);
  __syncthreads();
  int cur = 0;
  for (int ks = 0; ks < ksteps; ks++) {
    if (ks + 1 < ksteps) stage(cur ^ 1, ks + 1);
    const f16* sA = (const f16*)(SM + cur * 32768);
    const f16* sB = (const f16*)(SM + cur * 32768 + 16384);
#pragma unroll
    for (int kk = 0; kk < 2; kk++) {
      f16x8 af[2], bf[4];
#pragma unroll
      for (int i = 0; i < 2; i++) {
        int row = wm * 32 + i * 16 + l15;
        af[i] = *(const f16x8*)(sA + row * 64 + (((kk * 4 + l4) ^ (l15 & 7)) * 8));
      }
#pragma unroll
      for (int j = 0; j < 4; j++) {
        int row = wn * 64 + j * 16 + l15;
        bf[j] = *(const f16x8*)(sB + row * 64 + (((kk * 4 + l4) ^ (l15 & 7)) * 8));
      }
#pragma unroll
      for (int i = 0; i < 2; i++)
#pragma unroll
        for (int j = 0; j < 4; j++)
          acc[i][j] = __builtin_amdgcn_mfma_f32_16x16x32_f16(af[i], bf[j], acc[i][j], 0, 0, 0);
    }
    __syncthreads();
    cur ^= 1;
  }
  if (EPI == 0) {
#pragma unroll
    for (int i = 0; i < 2; i++) {
      int row = m0 + wm * 32 + i * 16 + l4 * 4;
#pragma unroll
      for (int j = 0; j < 4; j++) {
        int col = n0 + wn * 64 + j * 16 + l15;
#pragma unroll
        for (int r = 0; r < 4; r++) O[(size_t)(row + r) * 520 + col + 1] = acc[i][j][r];
      }
    }
  } else if (EPI == 1) {
    const int cb = (n0 >> 6) + wn;
    const int typ = cb >> 3, h = cb & 7;
    const float* bb = (typ == 0) ? c0 : (typ == 1) ? c1 : c2;
    float bj[4];
#pragma unroll
    for (int j = 0; j < 4; j++) bj[j] = bb[h * 64 + j * 16 + l15];
    const float qs = (typ == 0) ? 0.25f : 1.0f;
#pragma unroll
    for (int i = 0; i < 2; i++) {
#pragma unroll
      for (int r = 0; r < 4; r++) {
        float y[4], ss = 0.f;
#pragma unroll
        for (int j = 0; j < 4; j++) { y[j] = acc[i][j][r] + bj[j]; ss += y[j] * y[j]; }
        ss += __shfl_xor(ss, 1); ss += __shfl_xor(ss, 2);
        ss += __shfl_xor(ss, 4); ss += __shfl_xor(ss, 8);
        float t = sqrtf(ss + 1.f);
        int row = m0 + wm * 32 + i * 16 + l4 * 4 + r;
        int b = row >> 10, s = row & 1023, bh = b * 8 + h;
        if (typ < 2) {
          f16* dst = typ ? H2 : H1;
          size_t base = ((size_t)bh * 1024 + s) * 88;
#pragma unroll
          for (int j = 0; j < 4; j++) dst[base + j * 16 + l15] = (f16)(qs * y[j]);
          if (l15 == 0) dst[base + 64] = (f16)(qs * t);
        } else {
#pragma unroll
          for (int j = 0; j < 4; j++)
            H3[((size_t)bh * 80 + j * 16 + l15) * 1024 + s] = (f16)y[j];
          if (l15 == 0) H3[((size_t)bh * 80 + 64) * 1024 + s] = (f16)t;
        }
      }
    }
  } else if (EPI == 2) {
#pragma unroll
    for (int i = 0; i < 2; i++) {
#pragma unroll
      for (int r = 0; r < 4; r++) {
        int row = m0 + wm * 32 + i * 16 + l4 * 4 + r;
        float ss = 0.f;
#pragma unroll
        for (int j = 0; j < 4; j++) {
          int col = n0 + wn * 64 + j * 16 + l15;
          float gg = 0.f;
          if (col < 2047) {
            float yv = acc[i][j][r] + c0[col];
            float z = 0.7978845608f * (yv + 0.044715f * yv * yv * yv);
            float th = 1.f - 2.f / (__expf(2.f * z) + 1.f);
            gg = 0.5f * yv * (1.f + th);
          }
          ss += gg * gg;
          H1[(size_t)row * 2048 + col] = (f16)gg;
        }
        ss += __shfl_xor(ss, 1); ss += __shfl_xor(ss, 2);
        ss += __shfl_xor(ss, 4); ss += __shfl_xor(ss, 8);
        if (l15 == 0) atomicAdd(ssq + row, ss);
      }
    }
  } else {
#pragma unroll
    for (int i = 0; i < 2; i++) {
#pragma unroll
      for (int r = 0; r < 4; r++) {
        int row = m0 + wm * 32 + i * 16 + l4 * 4 + r;
        float t = addR1 ? sqrtf(ssq[row] + 1.f) : 0.f;
#pragma unroll
        for (int j = 0; j < 4; j++) {
          int col = n0 + wn * 64 + j * 16 + l15;
          float v = acc[i][j][r];
          if (addR1) v += t * ((col < 511) ? c0[col] : 0.f);
          O[(size_t)row * 520 + col + 1] = v;
        }
      }
    }
  }
}

// ---- per-wave flash attention + l_project ----
DEV void attn_task(int t, const f16* qhat, const f16* khat, const f16* vT, f16* ao,
                   char* sPb) {
  const int lane = threadIdx.x & 63;
  const int bh = t & 15, rt = 63 - (t >> 4);
  const int l15 = lane & 15, l4 = lane >> 4;
  f16* sP = (f16*)sPb;
  const f16* qp = qhat + ((size_t)bh * 1024 + rt * 16) * 88;
  const f16* kp = khat + (size_t)bh * 1024 * 88;
  const f16* vp = vT + (size_t)bh * 80 * 1024;
  f16x8 qf0 = *(const f16x8*)(qp + l15 * 88 + l4 * 8);
  f16x8 qf1 = *(const f16x8*)(qp + l15 * 88 + 32 + l4 * 8);
  float qth[4];
#pragma unroll
  for (int r = 0; r < 4; r++) qth[r] = (float)qp[(l4 * 4 + r) * 88 + 64];
  f32x4 acc[5];
#pragma unroll
  for (int i = 0; i < 5; i++) acc[i] = (f32x4){0, 0, 0, 0};
  float mrun[4] = {-3e38f, -3e38f, -3e38f, -3e38f}, lrun[4] = {0, 0, 0, 0};
  const int nt = (rt >> 2) + 1;
  for (int jt = 0; jt < nt; ++jt) {
    const int j0 = jt * 64;
    const bool dt = (jt == nt - 1);
    f32x4 sc[4];
#pragma unroll
    for (int fn = 0; fn < 4; fn++) {
      const f16* kb = kp + (size_t)(j0 + fn * 16 + l15) * 88;
      f16x8 k0v = *(const f16x8*)(kb + l4 * 8);
      f16x8 k1v = *(const f16x8*)(kb + 32 + l4 * 8);
      f32x4 a = (f32x4){0, 0, 0, 0};
      a = __builtin_amdgcn_mfma_f32_16x16x32_f16(qf0, k0v, a, 0, 0, 0);
      a = __builtin_amdgcn_mfma_f32_16x16x32_f16(qf1, k1v, a, 0, 0, 0);
      sc[fn] = a;
    }
    float s[4][4];
#pragma unroll
    for (int fn = 0; fn < 4; fn++) {
      float ktc = (float)kp[(size_t)(j0 + fn * 16 + l15) * 88 + 64];
      int col = j0 + fn * 16 + l15;
#pragma unroll
      for (int r = 0; r < 4; r++) {
        int row = rt * 16 + l4 * 4 + r;
        float v = sc[fn][r] - qth[r] * ktc;
        s[fn][r] = (!dt || col <= row) ? v : -3e38f;
      }
    }
    float mnew[4], al[4], rs[4];
#pragma unroll
    for (int r = 0; r < 4; r++) {
      float tm = fmaxf(fmaxf(s[0][r], s[1][r]), fmaxf(s[2][r], s[3][r]));
#pragma unroll
      for (int o = 8; o; o >>= 1) tm = fmaxf(tm, __shfl_xor(tm, o));
      mnew[r] = fmaxf(mrun[r], tm);
      al[r] = exp2f((mrun[r] - mnew[r]) * 1.44269504f);
      mrun[r] = mnew[r];
      rs[r] = 0.f;
    }
#pragma unroll
    for (int fn = 0; fn < 4; fn++)
#pragma unroll
      for (int r = 0; r < 4; r++) {
        float pv = exp2f((s[fn][r] - mnew[r]) * 1.44269504f);
        rs[r] += pv;
        sP[(l4 * 4 + r) * 88 + fn * 16 + l15] = (f16)pv;
      }
#pragma unroll
    for (int r = 0; r < 4; r++) {
#pragma unroll
      for (int o = 8; o; o >>= 1) rs[r] += __shfl_xor(rs[r], o);
      lrun[r] = lrun[r] * al[r] + rs[r];
    }
#pragma unroll
    for (int fd = 0; fd < 5; fd++)
#pragma unroll
      for (int r = 0; r < 4; r++) acc[fd][r] *= al[r];
    asm volatile("s_waitcnt lgkmcnt(0)" ::: "memory");
    __builtin_amdgcn_sched_barrier(0);
#pragma unroll
    for (int ks = 0; ks < 2; ks++) {
      f16x8 pf = *(const f16x8*)(sP + l15 * 88 + ks * 32 + l4 * 8);
#pragma unroll
      for (int fd = 0; fd < 5; fd++) {
        f16x8 vf = *(const f16x8*)(vp + (size_t)(fd * 16 + l15) * 1024 + j0 + ks * 32 + l4 * 8);
        acc[fd] = __builtin_amdgcn_mfma_f32_16x16x32_f16(pf, vf, acc[fd], 0, 0, 0);
      }
    }
  }
  const int b = bh >> 3, h = bh & 7;
#pragma unroll
  for (int r = 0; r < 4; r++) {
    float invl = 1.0f / lrun[r];
    float ss = 0.f, ov[4];
#pragma unroll
    for (int fd = 0; fd < 4; fd++) { ov[fd] = acc[fd][r] * invl; ss += ov[fd] * ov[fd]; }
#pragma unroll
    for (int o = 8; o; o >>= 1) ss += __shfl_xor(ss, o);
    float tv = acc[4][r] * invl;
    tv = __shfl(tv, lane & 48);
    float scp = rsqrtf(fmaxf(tv * tv - ss, 1e-6f));
    int row = rt * 16 + l4 * 4 + r;
    size_t rb = ((size_t)b * 1024 + row) * 640 + h * 65;
    if (l15 == 0) ao[rb] = (f16)(tv * scp);
#pragma unroll
    for (int fd = 0; fd < 4; fd++) ao[rb + 1 + fd * 16 + l15] = (f16)(ov[fd] * scp);
  }
}

// ---- per-wave residual + l_project (+ optional LN) ----
DEV void resproj_row(float (&xreg)[8], int row, const float* rA, const float* rB,
                     const float* rC, const float* rD, int np, const float* bias,
                     float rw, const float* g, const float* bsh, f16* act, int applyLN,
                     float* ssq) {
  const int lane = threadIdx.x & 63, cbase = lane * 8;
  const size_t rb = (size_t)row * 520 + cbase;
  float y[8];
  {
    f32x4 a0 = *(const f32x4*)(rA + rb), a1 = *(const f32x4*)(rA + rb + 4);
    f32x4 b0 = *(const f32x4*)(rB + rb), b1 = *(const f32x4*)(rB + rb + 4);
#pragma unroll
    for (int j = 0; j < 4; j++) { y[j] = a0[j] + b0[j]; y[4 + j] = a1[j] + b1[j]; }
    if (np == 4) {
      f32x4 c0v = *(const f32x4*)(rC + rb), c1v = *(const f32x4*)(rC + rb + 4);
      f32x4 d0 = *(const f32x4*)(rD + rb), d1 = *(const f32x4*)(rD + rb + 4);
#pragma unroll
      for (int j = 0; j < 4; j++) { y[j] += c0v[j] + d0[j]; y[4 + j] += c1v[j] + d1[j]; }
    }
  }
#pragma unroll
  for (int j = 0; j < 8; j++) {
    int c = cbase + j;
    y[j] = (c >= 1) ? (y[j] + bias[c - 1]) : 0.f;
  }
  float lss = 0.f;
#pragma unroll
  for (int j = 0; j < 8; j++) lss += y[j] * y[j];
  float tax = sqrtf(wsum(lss) + 1.f);
  float u[8];
#pragma unroll
  for (int j = 0; j < 8; j++) u[j] = xreg[j] + rw * y[j];
  if (lane == 0) u[0] = xreg[0] + rw * tax;
  float lsu = 0.f, lsu2 = 0.f;
#pragma unroll
  for (int j = 0; j < 8; j++) { lsu += u[j]; lsu2 += u[j] * u[j]; }
  if (lane == 0) { lsu -= u[0]; lsu2 -= u[0] * u[0]; }
  float su = wsum(lsu), su2 = wsum(lsu2);
  float ut = __shfl(u[0], 0);
  float scp = rsqrtf(fmaxf(ut * ut - su2, 1e-6f));
  float nx[8];
#pragma unroll
  for (int j = 0; j < 8; j++) { nx[j] = u[j] * scp; xreg[j] = nx[j]; }
  if (lane == 0) ssq[row] = 0.f;
  f16* ar = act + (size_t)row * 512;
  f16x8 ov;
  if (applyLN) {
    float mu = su * scp * (1.f / 511.f);
    float var = su2 * scp * scp * (1.f / 511.f) - mu * mu;
    float inv = rsqrtf(var + 1e-5f);
    float n[8], lsn = 0.f;
#pragma unroll
    for (int j = 0; j < 8; j++) {
      int c = cbase + j;
      float nv = (c >= 1) ? ((nx[j] - mu) * inv * g[c - 1] + bsh[c - 1]) : 0.f;
      n[j] = nv; lsn += nv * nv;
    }
    float t2 = sqrtf(wsum(lsn) + 1.f);
    if (lane == 0) n[0] = t2;
#pragma unroll
    for (int j = 0; j < 8; j++) ov[j] = (f16)n[j];
  } else {
#pragma unroll
    for (int j = 0; j < 8; j++) ov[j] = (f16)nx[j];
  }
  *(f16x8*)(ar + cbase) = ov;
}

DEV void embed_row(float (&xreg)[8], int row, const int* tok, const float* tbl,
                   const float* g, const float* bsh, f16* act, float* ssq) {
  const int lane = threadIdx.x & 63, cbase = lane * 8;
  const float* e = tbl + (size_t)tok[row] * 511;
  float ev[8];
#pragma unroll
  for (int j = 0; j < 8; j++) {
    int c = cbase + j;
    ev[j] = (c >= 1) ? e[c - 1] : 0.f;
  }
  float lss = 0.f, lsu = 0.f;
#pragma unroll
  for (int j = 0; j < 8; j++) { lss += ev[j] * ev[j]; lsu += ev[j]; }
  float ss = wsum(lss), su = wsum(lsu);
  float t = sqrtf(ss + 1.f);
#pragma unroll
  for (int j = 0; j < 8; j++) xreg[j] = ev[j];
  if (lane == 0) xreg[0] = t;
  float mu = su * (1.f / 511.f);
  float var = ss * (1.f / 511.f) - mu * mu;
  float inv = rsqrtf(var + 1e-5f);
  float n[8], lsn = 0.f;
#pragma unroll
  for (int j = 0; j < 8; j++) {
    int c = cbase + j;
    float nv = (c >= 1) ? ((ev[j] - mu) * inv * g[c - 1] + bsh[c - 1]) : 0.f;
    n[j] = nv; lsn += nv * nv;
  }
  float t2 = sqrtf(wsum(lsn) + 1.f);
  if (lane == 0) n[0] = t2;
  f16x8 ov;
#pragma unroll
  for (int j = 0; j < 8; j++) ov[j] = (f16)n[j];
  *(f16x8*)(act + (size_t)row * 512 + cbase) = ov;
  if (lane == 0) ssq[row] = 0.f;
}

DEV void final_row(int row, const float* raw, const float* bias, const float* g,
                   const float* bsh, float* out) {
  const int lane = threadIdx.x & 63, cbase = lane * 8;
  const size_t rb = (size_t)row * 520 + cbase;
  f32x4 a0 = *(const f32x4*)(raw + rb), a1 = *(const f32x4*)(raw + rb + 4);
  float y[8];
#pragma unroll
  for (int j = 0; j < 4; j++) { y[j] = a0[j]; y[4 + j] = a1[j]; }
  float lss = 0.f, lsu = 0.f;
#pragma unroll
  for (int j = 0; j < 8; j++) {
    int c = cbase + j;
    y[j] = (c >= 1) ? (y[j] + bias[c - 1]) : 0.f;
    lss += y[j] * y[j]; lsu += y[j];
  }
  float s2 = wsum(lss), su = wsum(lsu);
  float mu = su * (1.f / 511.f);
  float var = s2 * (1.f / 511.f) - mu * mu;
  float inv = rsqrtf(var + 1e-5f);
  float n[8], lsn = 0.f;
#pragma unroll
  for (int j = 0; j < 8; j++) {
    int c = cbase + j;
    float nv = (c >= 1) ? ((y[j] - mu) * inv * g[c - 1] + bsh[c - 1]) : 0.f;
    n[j] = nv; lsn += nv * nv;
  }
  float t2 = sqrtf(wsum(lsn) + 1.f);
  if (lane == 0) n[0] = t2;
  float* orow = out + (size_t)row * 512 + cbase;
  f32x4 o0, o1;
#pragma unroll
  for (int j = 0; j < 4; j++) { o0[j] = n[j]; o1[j] = n[4 + j]; }
  *(f32x4*)orow = o0;
  *(f32x4*)(orow + 4) = o1;
}

__global__ __launch_bounds__(512, 2) void k_mega(MP p) {
  const int wg = blockIdx.x, tid = threadIdx.x, wid = tid >> 6;
  __shared__ __align__(16) char SM[65536];
  float xreg[8];
  const int myrow = wg * 8 + wid;

  // ---- phase 0: weight transposes + pad-zero + embed ----
  for (int t = wg; t < 9472; t += 256) {
    const float* W; f16* D; int K, N, ldk, n0, k0;
    if (t < 2304) {
      int mat = t >> 6, tile = t & 63;
      int layer = mat / 3, typ = mat % 3;
      W = (typ == 0 ? p.Wq : typ == 1 ? p.Wk : p.Wv) + (size_t)layer * 262144;
      D = p.wqkvT + (size_t)layer * 786432 + (size_t)typ * 262144;
      K = 512; N = 512; ldk = 512; n0 = (tile >> 3) * 64; k0 = (tile & 7) * 64;
    } else if (t < 3264) {
      int id = t - 2304; int l = id / 80, tile = id % 80;
      W = p.Wo + (size_t)l * 265720; D = p.woT + (size_t)l * 327680;
      K = 520; N = 511; ldk = 640; n0 = (tile / 10) * 64; k0 = (tile % 10) * 64;
    } else if (t < 6336) {
      int id = t - 3264; int l = id >> 8, tile = id & 255;
      W = p.Wfc + (size_t)l * 1048064; D = p.wfcT + (size_t)l * 1048576;
      K = 512; N = 2047; ldk = 512; n0 = (tile >> 3) * 64; k0 = (tile & 7) * 64;
    } else if (t < 9408) {
      int id = t - 6336; int l = id >> 8, tile = id & 255;
      W = p.Wpr + (size_t)l * 1046528 + 511; D = p.wprT + (size_t)l * 1048576;
      K = 2047; N = 511; ldk = 2048; n0 = (tile >> 5) * 64; k0 = (tile & 31) * 64;
    } else {
      int id = t - 9408;
      W = p.Wfin; D = p.wfinT; K = 512; N = 511; ldk = 512;
      n0 = (id >> 3) * 64; k0 = (id & 7) * 64;
    }
    trans_tile(W, D, K, N, ldk, n0, k0, SM);
  }
  for (int i = wg * 512 + tid; i < 2048 * 120; i += 256 * 512)
    p.ao[(size_t)(i / 120) * 640 + 520 + (i % 120)] = (f16)0.f;
  embed_row(xreg, myrow, p.tok, p.etab, p.ln1g, p.ln1b, p.actA, p.ssq);
  gbar(p);

  for (int li = 0; li < 12; li++) {
    const f16* wqkvT_l = p.wqkvT + (size_t)li * 786432;
    const f16* woT_l = p.woT + (size_t)li * 327680;
    const f16* wfcT_l = p.wfcT + (size_t)li * 1048576;
    const f16* wprT_l = p.wprT + (size_t)li * 1048576;
    const float* bq_l = p.bq + li * 512;
    const float* bk_l = p.bk + li * 512;
    const float* bv_l = p.bv + li * 512;
    const float* bo_l = p.bo + li * 511;
    const float* bfc_l = p.bfc + li * 2047;
    const float* bpr_l = p.bpr + li * 511;
    const float* w0_l = p.Wpr + (size_t)li * 1046528;

    for (int t = wg; t < 192; t += 256)
      gemm_task<1>(p.actA, wqkvT_l, 512, 512, t / 12, t % 12, 0, 8, nullptr,
                   bq_l, bk_l, bv_l, nullptr, p.qhat, p.khat, p.vT, 0, SM);
    gbar(p);
    if (wid < 4) attn_task(wid * 256 + wg, p.qhat, p.khat, p.vT, p.ao, SM + wid * 2816);
    gbar(p);
    for (int t = wg; t < 128; t += 256) {
      int tm = t >> 3, tn = (t >> 1) & 3, tz = t & 1;
      gemm_task<0>(p.ao, woT_l, 640, 640, tm, tn, tz * 320, 5,
                   tz ? p.rawB : p.rawA, nullptr, nullptr, nullptr, nullptr,
                   nullptr, nullptr, nullptr, 0, SM);
    }
    gbar(p);
    resproj_row(xreg, myrow, p.rawA, p.rawB, nullptr, nullptr, 2, bo_l, p.rw1[li],
                p.ln2g + li * 511, p.ln2b + li * 511, p.actA, 1, p.ssq);
    gbar(p);
    for (int t = wg; t < 256; t += 256)
      gemm_task<2>(p.actA, wfcT_l, 512, 512, t >> 4, t & 15, 0, 8, nullptr,
                   bfc_l, nullptr, nullptr, p.ssq, p.fcact, nullptr, nullptr, 0, SM);
    gbar(p);
    for (int t = wg; t < 256; t += 256) {
      int tm = t >> 4, tn = (t >> 2) & 3, tz = t & 3;
      float* O = tz == 0 ? p.rawA : tz == 1 ? p.rawB : tz == 2 ? p.rawC : p.rawD;
      gemm_task<3>(p.fcact, wprT_l, 2048, 2048, tm, tn, tz * 512, 8, O,
                   w0_l, nullptr, nullptr, p.ssq, nullptr, nullptr, nullptr, tz == 0, SM);
    }
    gbar(p);
    const float* ng = (li < 11) ? p.ln1g + (li + 1) * 511 : p.ln1g;
    const float* nb = (li < 11) ? p.ln1b + (li + 1) * 511 : p.ln1b;
    resproj_row(xreg, myrow, p.rawA, p.rawB, p.rawC, p.rawD, 4, bpr_l, p.rw2[li],
                ng, nb, p.actA, (li < 11) ? 1 : 0, p.ssq);
    gbar(p);
  }

  for (int t = wg; t < 64; t += 256)
    gemm_task<0>(p.actA, p.wfinT, 512, 512, t >> 2, t & 3, 0, 8, p.rawA,
                 nullptr, nullptr, nullptr, nullptr, nullptr, nullptr, nullptr, 0, SM);
  gbar(p);
  final_row(myrow, p.rawA, p.bfin, p.lnfg, p.lnfb, p.out);
}

extern "C" void kernel_launch(void* const* d_in, const int* in_sizes, int n_in,
                              void* d_out, int out_size, void* d_ws, size_t ws_size,
                              hipStream_t stream) {
  (void)in_sizes; (void)n_in; (void)out_size; (void)ws_size;
  MP p;
  p.tok = (const int*)d_in[0];
  p.etab = (const float*)d_in[1];
  p.Wq = (const float*)d_in[2];  p.bq = (const float*)d_in[3];
  p.Wk = (const float*)d_in[4];  p.bk = (const float*)d_in[5];
  p.Wv = (const float*)d_in[6];  p.bv = (const float*)d_in[7];
  p.Wo = (const float*)d_in[8];  p.bo = (const float*)d_in[9];
  p.ln1g = (const float*)d_in[10]; p.ln1b = (const float*)d_in[11];
  p.ln2g = (const float*)d_in[12]; p.ln2b = (const float*)d_in[13];
  p.Wfc = (const float*)d_in[14]; p.bfc = (const float*)d_in[15];
  p.Wpr = (const float*)d_in[16]; p.bpr = (const float*)d_in[17];
  p.rw1 = (const float*)d_in[18]; p.rw2 = (const float*)d_in[19];
  p.Wfin = (const float*)d_in[20]; p.bfin = (const float*)d_in[21];
  p.lnfg = (const float*)d_in[22]; p.lnfb = (const float*)d_in[23];

  char* wsb = (char*)d_ws;
  size_t off = 0;
  auto alloc = [&](size_t bytes) -> char* {
    char* q = wsb + off;
    off = (off + bytes + 1023) & ~(size_t)1023;
    return q;
  };
  p.actA = (f16*)alloc(2048ull * 512 * 2);
  p.rawA = (float*)alloc(2048ull * 520 * 4);
  p.rawB = (float*)alloc(2048ull * 520 * 4);
  p.rawC = (float*)alloc(2048ull * 520 * 4);
  p.rawD = (float*)alloc(2048ull * 520 * 4);
  p.ssq = (float*)alloc(2048ull * 4);
  p.qhat = (f16*)alloc(16ull * 1024 * 88 * 2);
  p.khat = (f16*)alloc(16ull * 1024 * 88 * 2);
  p.vT = (f16*)alloc(16ull * 80 * 1024 * 2);
  p.ao = (f16*)alloc(2048ull * 640 * 2);
  p.fcact = (f16*)alloc(2048ull * 2048 * 2);
  p.wqkvT = (f16*)alloc(12ull * 786432 * 2);
  p.woT = (f16*)alloc(12ull * 327680 * 2);
  p.wfcT = (f16*)alloc(12ull * 1048576 * 2);
  p.wprT = (f16*)alloc(12ull * 1048576 * 2);
  p.wfinT = (f16*)alloc(512ull * 512 * 2);
  p.bar = (u32*)alloc(4096);
  p.out = (float*)d_out;

  hipMemsetAsync(p.bar, 0, 4096, stream);
  k_mega<<<256, 512, 0, stream>>>(p);
}

// Round 5
// 2184.405 us; speedup vs baseline: 2.4848x; 1.1553x over previous
//
#include <hip/hip_runtime.h>
#include <cstdint>

typedef _Float16 f16;
typedef _Float16 f16x8 __attribute__((ext_vector_type(8)));
typedef float f32x4 __attribute__((ext_vector_type(4)));
typedef unsigned int u32;

#define DEV __device__ __forceinline__

DEV void gll16(const void* g, void* l) {
  __builtin_amdgcn_global_load_lds((const __attribute__((address_space(1))) u32*)g,
                                   (__attribute__((address_space(3))) u32*)l, 16, 0, 0);
}

DEV float wsum(float v) {
#pragma unroll
  for (int o = 32; o; o >>= 1) v += __shfl_xor(v, o);
  return v;
}

struct MP {
  const int* tok; const float* etab;
  const float* Wq; const float* bq; const float* Wk; const float* bk;
  const float* Wv; const float* bv; const float* Wo; const float* bo;
  const float* ln1g; const float* ln1b; const float* ln2g; const float* ln2b;
  const float* Wfc; const float* bfc; const float* Wpr; const float* bpr;
  const float* rw1; const float* rw2; const float* Wfin; const float* bfin;
  const float* lnfg; const float* lnfb;
  f16* actA; float* rawA; float* rawB; float* rawC; float* rawD; float* ssq;
  f16* qhat; f16* khat; f16* vT; f16* ao; f16* fcact;
  f16* wqkvT; f16* woT; f16* wfcT; f16* wprT; f16* wfinT;
  u32* bar; float* out;
};

// bar layout (u32 idx): root=0, gen=32, cnt[x]=64+32x, nblk[x]=320+x, root0=352, gen0=384
DEV u32 ld_rlx(u32* p) { return __hip_atomic_load(p, __ATOMIC_RELAXED, __HIP_MEMORY_SCOPE_AGENT); }
DEV u32 inc_rlx(u32* p) { return __hip_atomic_fetch_add(p, 1u, __ATOMIC_RELAXED, __HIP_MEMORY_SCOPE_AGENT); }

// ---- one-time init barrier: flat 256, full fences ----
DEV void gbar_init(u32* bar) {
  __syncthreads();
  if (threadIdx.x == 0) {
    u32* root0 = bar + 352;
    u32* gen0 = bar + 384;
    u32 g = ld_rlx(gen0);
    __builtin_amdgcn_fence(__ATOMIC_RELEASE, "agent");
    u32 a = inc_rlx(root0);
    if ((a & 255u) == 255u) {
      __hip_atomic_store(gen0, g + 1u, __ATOMIC_RELEASE, __HIP_MEMORY_SCOPE_AGENT);
    } else {
      for (int it = 0; it < (1 << 22); ++it) {
        if (ld_rlx(gen0) != g) break;
        __builtin_amdgcn_s_sleep(2);
      }
    }
    __builtin_amdgcn_fence(__ATOMIC_ACQUIRE, "agent");
  }
  __syncthreads();
}

// ---- fast barrier: leader-only L2 writeback per XCD ----
DEV void gbar2(u32* bar, u32 myxcc, u32 Nx, u32 NXCD) {
  __syncthreads();
  if (threadIdx.x == 0) {
    u32* cnt = bar + 64 + myxcc * 32;
    u32* root = bar + 0;
    u32* gen = bar + 32;
    u32 g = ld_rlx(gen);
    asm volatile("s_waitcnt vmcnt(0) lgkmcnt(0)" ::: "memory");
    u32 a = inc_rlx(cnt);
    bool flipped = false;
    if (a % Nx == Nx - 1u) {   // last arriver on this XCD: flush this XCD's L2
      __builtin_amdgcn_fence(__ATOMIC_RELEASE, "agent");
      asm volatile("s_waitcnt vmcnt(0)" ::: "memory");
      u32 b = inc_rlx(root);
      if (b % NXCD == NXCD - 1u) {
        __hip_atomic_store(gen, g + 1u, __ATOMIC_RELEASE, __HIP_MEMORY_SCOPE_AGENT);
        flipped = true;
      }
    }
    if (!flipped) {
      for (int it = 0; it < (1 << 22); ++it) {
        if (ld_rlx(gen) != g) break;
        __builtin_amdgcn_s_sleep(2);
      }
    }
    __builtin_amdgcn_fence(__ATOMIC_ACQUIRE, "agent");
  }
  __syncthreads();
}

// ---- 64x64 f32->f16 transpose tile through LDS ----
DEV void trans_tile(const float* W, f16* BT, int K, int N, int ldk, int n0, int k0,
                    char* SM) {
  float* tile = (float*)SM;  // [64][65]
  const int tid = threadIdx.x;
  const int c = tid & 63, r0 = tid >> 6;
#pragma unroll
  for (int i = 0; i < 8; i++) {
    int kr = r0 + i * 8;
    int k = k0 + kr, n = n0 + c;
    tile[kr * 65 + c] = (k < K && n < N) ? W[(size_t)k * N + n] : 0.f;
  }
  __syncthreads();
#pragma unroll
  for (int i = 0; i < 8; i++) {
    int nn = r0 + i * 8;
    BT[(size_t)(n0 + nn) * ldk + k0 + c] = (f16)tile[c * 65 + nn];
  }
  __syncthreads();
}

// ---- 128x128 GEMM task, BK=64, true dbuf: raw s_barrier + counted vmcnt ----
template <int EPI>
DEV void gemm_task(const f16* A, const f16* B, int lda, int ldb, int tm, int tn,
                   int kbeg, int ksteps, float* O, const float* c0, const float* c1,
                   const float* c2, float* ssq, f16* H1, f16* H2, f16* H3,
                   int addR1, char* SM) {
  const int tid = threadIdx.x, wid = tid >> 6, lane = tid & 63;
  const int l15 = lane & 15, l4 = lane >> 4;
  const int wm = wid & 3, wn = wid >> 2;
  const int m0 = tm * 128, n0 = tn * 128;
  f32x4 acc[2][4];
#pragma unroll
  for (int i = 0; i < 2; i++)
#pragma unroll
    for (int j = 0; j < 4; j++) acc[i][j] = (f32x4){0.f, 0.f, 0.f, 0.f};
  const size_t ldab = (size_t)lda * 2, ldbb = (size_t)ldb * 2;
  const int swz = ((lane & 7) ^ (lane >> 3)) * 16;
  const char* Ab = (const char*)A + (size_t)(m0 + (lane >> 3)) * ldab + swz + (size_t)kbeg * 2;
  const char* Bb = (const char*)B + (size_t)(n0 + (lane >> 3)) * ldbb + swz + (size_t)kbeg * 2;
  auto stage = [&](int buf, int ks) {  // 4 gll16 per wave
    char* da = SM + buf * 32768;
    char* db = da + 16384;
    for (int i = wid; i < 16; i += 8) gll16(Ab + (size_t)(i * 8) * ldab + ks * 128, da + i * 1024);
    for (int i = wid; i < 16; i += 8) gll16(Bb + (size_t)(i * 8) * ldbb + ks * 128, db + i * 1024);
  };
  stage(0, 0);
  asm volatile("s_waitcnt vmcnt(0)" ::: "memory");
  __builtin_amdgcn_s_barrier();
  __builtin_amdgcn_sched_barrier(0);
  int cur = 0;
  for (int ks = 0; ks < ksteps; ks++) {
    if (ks + 1 < ksteps) {
      stage(cur ^ 1, ks + 1);                       // prefetch flies over this step's MFMA
      asm volatile("s_waitcnt vmcnt(4)" ::: "memory");  // wait only cur's 4 loads
    } else {
      asm volatile("s_waitcnt vmcnt(0)" ::: "memory");
    }
    __builtin_amdgcn_s_barrier();                   // all waves' cur-tile staged
    __builtin_amdgcn_sched_barrier(0);
    const f16* sA = (const f16*)(SM + cur * 32768);
    const f16* sB = (const f16*)(SM + cur * 32768 + 16384);
#pragma unroll
    for (int kk = 0; kk < 2; kk++) {
      f16x8 af[2], bf[4];
#pragma unroll
      for (int i = 0; i < 2; i++) {
        int row = wm * 32 + i * 16 + l15;
        af[i] = *(const f16x8*)(sA + row * 64 + (((kk * 4 + l4) ^ (l15 & 7)) * 8));
      }
#pragma unroll
      for (int j = 0; j < 4; j++) {
        int row = wn * 64 + j * 16 + l15;
        bf[j] = *(const f16x8*)(sB + row * 64 + (((kk * 4 + l4) ^ (l15 & 7)) * 8));
      }
#pragma unroll
      for (int i = 0; i < 2; i++)
#pragma unroll
        for (int j = 0; j < 4; j++)
          acc[i][j] = __builtin_amdgcn_mfma_f32_16x16x32_f16(af[i], bf[j], acc[i][j], 0, 0, 0);
    }
    __builtin_amdgcn_sched_barrier(0);
    __builtin_amdgcn_s_barrier();                   // all waves done reading cur
    cur ^= 1;
  }
  if (EPI == 0) {
#pragma unroll
    for (int i = 0; i < 2; i++) {
      int row = m0 + wm * 32 + i * 16 + l4 * 4;
#pragma unroll
      for (int j = 0; j < 4; j++) {
        int col = n0 + wn * 64 + j * 16 + l15;
#pragma unroll
        for (int r = 0; r < 4; r++) O[(size_t)(row + r) * 520 + col + 1] = acc[i][j][r];
      }
    }
  } else if (EPI == 1) {
    const int cb = (n0 >> 6) + wn;
    const int typ = cb >> 3, h = cb & 7;
    const float* bb = (typ == 0) ? c0 : (typ == 1) ? c1 : c2;
    float bj[4];
#pragma unroll
    for (int j = 0; j < 4; j++) bj[j] = bb[h * 64 + j * 16 + l15];
    const float qs = (typ == 0) ? 0.25f : 1.0f;
#pragma unroll
    for (int i = 0; i < 2; i++) {
#pragma unroll
      for (int r = 0; r < 4; r++) {
        float y[4], ss = 0.f;
#pragma unroll
        for (int j = 0; j < 4; j++) { y[j] = acc[i][j][r] + bj[j]; ss += y[j] * y[j]; }
        ss += __shfl_xor(ss, 1); ss += __shfl_xor(ss, 2);
        ss += __shfl_xor(ss, 4); ss += __shfl_xor(ss, 8);
        float t = sqrtf(ss + 1.f);
        int row = m0 + wm * 32 + i * 16 + l4 * 4 + r;
        int b = row >> 10, s = row & 1023, bh = b * 8 + h;
        if (typ < 2) {
          f16* dst = typ ? H2 : H1;
          size_t base = ((size_t)bh * 1024 + s) * 88;
#pragma unroll
          for (int j = 0; j < 4; j++) dst[base + j * 16 + l15] = (f16)(qs * y[j]);
          if (l15 == 0) dst[base + 64] = (f16)(qs * t);
        } else {
#pragma unroll
          for (int j = 0; j < 4; j++)
            H3[((size_t)bh * 80 + j * 16 + l15) * 1024 + s] = (f16)y[j];
          if (l15 == 0) H3[((size_t)bh * 80 + 64) * 1024 + s] = (f16)t;
        }
      }
    }
  } else if (EPI == 2) {
#pragma unroll
    for (int i = 0; i < 2; i++) {
#pragma unroll
      for (int r = 0; r < 4; r++) {
        int row = m0 + wm * 32 + i * 16 + l4 * 4 + r;
        float ss = 0.f;
#pragma unroll
        for (int j = 0; j < 4; j++) {
          int col = n0 + wn * 64 + j * 16 + l15;
          float gg = 0.f;
          if (col < 2047) {
            float yv = acc[i][j][r] + c0[col];
            float z = 0.7978845608f * (yv + 0.044715f * yv * yv * yv);
            float th = 1.f - 2.f / (__expf(2.f * z) + 1.f);
            gg = 0.5f * yv * (1.f + th);
          }
          ss += gg * gg;
          H1[(size_t)row * 2048 + col] = (f16)gg;
        }
        ss += __shfl_xor(ss, 1); ss += __shfl_xor(ss, 2);
        ss += __shfl_xor(ss, 4); ss += __shfl_xor(ss, 8);
        if (l15 == 0) atomicAdd(ssq + row, ss);
      }
    }
  } else {
#pragma unroll
    for (int i = 0; i < 2; i++) {
#pragma unroll
      for (int r = 0; r < 4; r++) {
        int row = m0 + wm * 32 + i * 16 + l4 * 4 + r;
        float t = addR1 ? sqrtf(ssq[row] + 1.f) : 0.f;
#pragma unroll
        for (int j = 0; j < 4; j++) {
          int col = n0 + wn * 64 + j * 16 + l15;
          float v = acc[i][j][r];
          if (addR1) v += t * ((col < 511) ? c0[col] : 0.f);
          O[(size_t)row * 520 + col + 1] = v;
        }
      }
    }
  }
}

// ---- per-wave flash attention + l_project ----
DEV void attn_task(int t, const f16* qhat, const f16* khat, const f16* vT, f16* ao,
                   char* sPb) {
  const int lane = threadIdx.x & 63;
  const int bh = t & 15, rt = 63 - (t >> 4);
  const int l15 = lane & 15, l4 = lane >> 4;
  f16* sP = (f16*)sPb;
  const f16* qp = qhat + ((size_t)bh * 1024 + rt * 16) * 88;
  const f16* kp = khat + (size_t)bh * 1024 * 88;
  const f16* vp = vT + (size_t)bh * 80 * 1024;
  f16x8 qf0 = *(const f16x8*)(qp + l15 * 88 + l4 * 8);
  f16x8 qf1 = *(const f16x8*)(qp + l15 * 88 + 32 + l4 * 8);
  float qth[4];
#pragma unroll
  for (int r = 0; r < 4; r++) qth[r] = (float)qp[(l4 * 4 + r) * 88 + 64];
  f32x4 acc[5];
#pragma unroll
  for (int i = 0; i < 5; i++) acc[i] = (f32x4){0, 0, 0, 0};
  float mrun[4] = {-3e38f, -3e38f, -3e38f, -3e38f}, lrun[4] = {0, 0, 0, 0};
  const int nt = (rt >> 2) + 1;
  for (int jt = 0; jt < nt; ++jt) {
    const int j0 = jt * 64;
    const bool dt = (jt == nt - 1);
    f32x4 sc[4];
#pragma unroll
    for (int fn = 0; fn < 4; fn++) {
      const f16* kb = kp + (size_t)(j0 + fn * 16 + l15) * 88;
      f16x8 k0v = *(const f16x8*)(kb + l4 * 8);
      f16x8 k1v = *(const f16x8*)(kb + 32 + l4 * 8);
      f32x4 a = (f32x4){0, 0, 0, 0};
      a = __builtin_amdgcn_mfma_f32_16x16x32_f16(qf0, k0v, a, 0, 0, 0);
      a = __builtin_amdgcn_mfma_f32_16x16x32_f16(qf1, k1v, a, 0, 0, 0);
      sc[fn] = a;
    }
    float s[4][4];
#pragma unroll
    for (int fn = 0; fn < 4; fn++) {
      float ktc = (float)kp[(size_t)(j0 + fn * 16 + l15) * 88 + 64];
      int col = j0 + fn * 16 + l15;
#pragma unroll
      for (int r = 0; r < 4; r++) {
        int row = rt * 16 + l4 * 4 + r;
        float v = sc[fn][r] - qth[r] * ktc;
        s[fn][r] = (!dt || col <= row) ? v : -3e38f;
      }
    }
    float mnew[4], al[4], rs[4];
#pragma unroll
    for (int r = 0; r < 4; r++) {
      float tm = fmaxf(fmaxf(s[0][r], s[1][r]), fmaxf(s[2][r], s[3][r]));
#pragma unroll
      for (int o = 8; o; o >>= 1) tm = fmaxf(tm, __shfl_xor(tm, o));
      mnew[r] = fmaxf(mrun[r], tm);
      al[r] = exp2f((mrun[r] - mnew[r]) * 1.44269504f);
      mrun[r] = mnew[r];
      rs[r] = 0.f;
    }
#pragma unroll
    for (int fn = 0; fn < 4; fn++)
#pragma unroll
      for (int r = 0; r < 4; r++) {
        float pv = exp2f((s[fn][r] - mnew[r]) * 1.44269504f);
        rs[r] += pv;
        sP[(l4 * 4 + r) * 88 + fn * 16 + l15] = (f16)pv;
      }
#pragma unroll
    for (int r = 0; r < 4; r++) {
#pragma unroll
      for (int o = 8; o; o >>= 1) rs[r] += __shfl_xor(rs[r], o);
      lrun[r] = lrun[r] * al[r] + rs[r];
    }
#pragma unroll
    for (int fd = 0; fd < 5; fd++)
#pragma unroll
      for (int r = 0; r < 4; r++) acc[fd][r] *= al[r];
    asm volatile("s_waitcnt lgkmcnt(0)" ::: "memory");
    __builtin_amdgcn_sched_barrier(0);
#pragma unroll
    for (int ks = 0; ks < 2; ks++) {
      f16x8 pf = *(const f16x8*)(sP + l15 * 88 + ks * 32 + l4 * 8);
#pragma unroll
      for (int fd = 0; fd < 5; fd++) {
        f16x8 vf = *(const f16x8*)(vp + (size_t)(fd * 16 + l15) * 1024 + j0 + ks * 32 + l4 * 8);
        acc[fd] = __builtin_amdgcn_mfma_f32_16x16x32_f16(pf, vf, acc[fd], 0, 0, 0);
      }
    }
  }
  const int b = bh >> 3, h = bh & 7;
#pragma unroll
  for (int r = 0; r < 4; r++) {
    float invl = 1.0f / lrun[r];
    float ss = 0.f, ov[4];
#pragma unroll
    for (int fd = 0; fd < 4; fd++) { ov[fd] = acc[fd][r] * invl; ss += ov[fd] * ov[fd]; }
#pragma unroll
    for (int o = 8; o; o >>= 1) ss += __shfl_xor(ss, o);
    float tv = acc[4][r] * invl;
    tv = __shfl(tv, lane & 48);
    float scp = rsqrtf(fmaxf(tv * tv - ss, 1e-6f));
    int row = rt * 16 + l4 * 4 + r;
    size_t rb = ((size_t)b * 1024 + row) * 640 + h * 65;
    if (l15 == 0) ao[rb] = (f16)(tv * scp);
#pragma unroll
    for (int fd = 0; fd < 4; fd++) ao[rb + 1 + fd * 16 + l15] = (f16)(ov[fd] * scp);
  }
}

// ---- per-wave residual + l_project (+ optional LN) ----
DEV void resproj_row(float (&xreg)[8], int row, const float* rA, const float* rB,
                     const float* rC, const float* rD, int np, const float* bias,
                     float rw, const float* g, const float* bsh, f16* act, int applyLN,
                     float* ssq) {
  const int lane = threadIdx.x & 63, cbase = lane * 8;
  const size_t rb = (size_t)row * 520 + cbase;
  float y[8];
  {
    f32x4 a0 = *(const f32x4*)(rA + rb), a1 = *(const f32x4*)(rA + rb + 4);
    f32x4 b0 = *(const f32x4*)(rB + rb), b1 = *(const f32x4*)(rB + rb + 4);
#pragma unroll
    for (int j = 0; j < 4; j++) { y[j] = a0[j] + b0[j]; y[4 + j] = a1[j] + b1[j]; }
    if (np == 4) {
      f32x4 c0v = *(const f32x4*)(rC + rb), c1v = *(const f32x4*)(rC + rb + 4);
      f32x4 d0 = *(const f32x4*)(rD + rb), d1 = *(const f32x4*)(rD + rb + 4);
#pragma unroll
      for (int j = 0; j < 4; j++) { y[j] += c0v[j] + d0[j]; y[4 + j] += c1v[j] + d1[j]; }
    }
  }
#pragma unroll
  for (int j = 0; j < 8; j++) {
    int c = cbase + j;
    y[j] = (c >= 1) ? (y[j] + bias[c - 1]) : 0.f;
  }
  float lss = 0.f;
#pragma unroll
  for (int j = 0; j < 8; j++) lss += y[j] * y[j];
  float tax = sqrtf(wsum(lss) + 1.f);
  float u[8];
#pragma unroll
  for (int j = 0; j < 8; j++) u[j] = xreg[j] + rw * y[j];
  if (lane == 0) u[0] = xreg[0] + rw * tax;
  float lsu = 0.f, lsu2 = 0.f;
#pragma unroll
  for (int j = 0; j < 8; j++) { lsu += u[j]; lsu2 += u[j] * u[j]; }
  if (lane == 0) { lsu -= u[0]; lsu2 -= u[0] * u[0]; }
  float su = wsum(lsu), su2 = wsum(lsu2);
  float ut = __shfl(u[0], 0);
  float scp = rsqrtf(fmaxf(ut * ut - su2, 1e-6f));
  float nx[8];
#pragma unroll
  for (int j = 0; j < 8; j++) { nx[j] = u[j] * scp; xreg[j] = nx[j]; }
  if (lane == 0) ssq[row] = 0.f;
  f16* ar = act + (size_t)row * 512;
  f16x8 ov;
  if (applyLN) {
    float mu = su * scp * (1.f / 511.f);
    float var = su2 * scp * scp * (1.f / 511.f) - mu * mu;
    float inv = rsqrtf(var + 1e-5f);
    float n[8], lsn = 0.f;
#pragma unroll
    for (int j = 0; j < 8; j++) {
      int c = cbase + j;
      float nv = (c >= 1) ? ((nx[j] - mu) * inv * g[c - 1] + bsh[c - 1]) : 0.f;
      n[j] = nv; lsn += nv * nv;
    }
    float t2 = sqrtf(wsum(lsn) + 1.f);
    if (lane == 0) n[0] = t2;
#pragma unroll
    for (int j = 0; j < 8; j++) ov[j] = (f16)n[j];
  } else {
#pragma unroll
    for (int j = 0; j < 8; j++) ov[j] = (f16)nx[j];
  }
  *(f16x8*)(ar + cbase) = ov;
}

DEV void embed_row(float (&xreg)[8], int row, const int* tok, const float* tbl,
                   const float* g, const float* bsh, f16* act, float* ssq) {
  const int lane = threadIdx.x & 63, cbase = lane * 8;
  const float* e = tbl + (size_t)tok[row] * 511;
  float ev[8];
#pragma unroll
  for (int j = 0; j < 8; j++) {
    int c = cbase + j;
    ev[j] = (c >= 1) ? e[c - 1] : 0.f;
  }
  float lss = 0.f, lsu = 0.f;
#pragma unroll
  for (int j = 0; j < 8; j++) { lss += ev[j] * ev[j]; lsu += ev[j]; }
  float ss = wsum(lss), su = wsum(lsu);
  float t = sqrtf(ss + 1.f);
#pragma unroll
  for (int j = 0; j < 8; j++) xreg[j] = ev[j];
  if (lane == 0) xreg[0] = t;
  float mu = su * (1.f / 511.f);
  float var = ss * (1.f / 511.f) - mu * mu;
  float inv = rsqrtf(var + 1e-5f);
  float n[8], lsn = 0.f;
#pragma unroll
  for (int j = 0; j < 8; j++) {
    int c = cbase + j;
    float nv = (c >= 1) ? ((ev[j] - mu) * inv * g[c - 1] + bsh[c - 1]) : 0.f;
    n[j] = nv; lsn += nv * nv;
  }
  float t2 = sqrtf(wsum(lsn) + 1.f);
  if (lane == 0) n[0] = t2;
  f16x8 ov;
#pragma unroll
  for (int j = 0; j < 8; j++) ov[j] = (f16)n[j];
  *(f16x8*)(act + (size_t)row * 512 + cbase) = ov;
  if (lane == 0) ssq[row] = 0.f;
}

DEV void final_row(int row, const float* raw, const float* bias, const float* g,
                   const float* bsh, float* out) {
  const int lane = threadIdx.x & 63, cbase = lane * 8;
  const size_t rb = (size_t)row * 520 + cbase;
  f32x4 a0 = *(const f32x4*)(raw + rb), a1 = *(const f32x4*)(raw + rb + 4);
  float y[8];
#pragma unroll
  for (int j = 0; j < 4; j++) { y[j] = a0[j]; y[4 + j] = a1[j]; }
  float lss = 0.f, lsu = 0.f;
#pragma unroll
  for (int j = 0; j < 8; j++) {
    int c = cbase + j;
    y[j] = (c >= 1) ? (y[j] + bias[c - 1]) : 0.f;
    lss += y[j] * y[j]; lsu += y[j];
  }
  float s2 = wsum(lss), su = wsum(lsu);
  float mu = su * (1.f / 511.f);
  float var = s2 * (1.f / 511.f) - mu * mu;
  float inv = rsqrtf(var + 1e-5f);
  float n[8], lsn = 0.f;
#pragma unroll
  for (int j = 0; j < 8; j++) {
    int c = cbase + j;
    float nv = (c >= 1) ? ((y[j] - mu) * inv * g[c - 1] + bsh[c - 1]) : 0.f;
    n[j] = nv; lsn += nv * nv;
  }
  float t2 = sqrtf(wsum(lsn) + 1.f);
  if (lane == 0) n[0] = t2;
  float* orow = out + (size_t)row * 512 + cbase;
  f32x4 o0, o1;
#pragma unroll
  for (int j = 0; j < 4; j++) { o0[j] = n[j]; o1[j] = n[4 + j]; }
  *(f32x4*)orow = o0;
  *(f32x4*)(orow + 4) = o1;
}

__global__ __launch_bounds__(512, 2) void k_mega(MP p) {
  const int tid = threadIdx.x, wid = tid >> 6;
  __shared__ __align__(16) char SM[65536];
  __shared__ u32 hdr[4];  // lx, Nx, NXCD, prefix
  float xreg[8];

  // ---- init: discover XCD topology, establish per-XCD leader counts ----
  u32 myxcc;
  asm volatile("s_getreg_b32 %0, hwreg(HW_REG_XCC_ID)" : "=s"(myxcc));
  myxcc &= 7;
  if (tid == 0) hdr[0] = inc_rlx(p.bar + 320 + myxcc);
  gbar_init(p.bar);
  if (tid == 0) {
    u32 nx = 0, nxcd = 0, pre = 0;
#pragma unroll
    for (int x = 0; x < 8; x++) {
      u32 c = ld_rlx(p.bar + 320 + x);
      if (c) nxcd++;
      if ((u32)x < myxcc) pre += c;
      if ((u32)x == myxcc) nx = c;
    }
    hdr[1] = nx; hdr[2] = nxcd; hdr[3] = pre;
  }
  __syncthreads();
  const u32 Nx = hdr[1], NXCD = hdr[2];
  const int tt = (int)(hdr[3] + hdr[0]);  // XCD-contiguous block rank, 0..255
  __syncthreads();
  const int myrow = tt * 8 + wid;

  // ---- phase 0: weight transposes + pad-zero + embed ----
  for (int t = tt; t < 9472; t += 256) {
    const float* W; f16* D; int K, N, ldk, n0, k0;
    if (t < 2304) {
      int mat = t >> 6, tile = t & 63;
      int layer = mat / 3, typ = mat % 3;
      W = (typ == 0 ? p.Wq : typ == 1 ? p.Wk : p.Wv) + (size_t)layer * 262144;
      D = p.wqkvT + (size_t)layer * 786432 + (size_t)typ * 262144;
      K = 512; N = 512; ldk = 512; n0 = (tile >> 3) * 64; k0 = (tile & 7) * 64;
    } else if (t < 3264) {
      int id = t - 2304; int l = id / 80, tile = id % 80;
      W = p.Wo + (size_t)l * 265720; D = p.woT + (size_t)l * 327680;
      K = 520; N = 511; ldk = 640; n0 = (tile / 10) * 64; k0 = (tile % 10) * 64;
    } else if (t < 6336) {
      int id = t - 3264; int l = id >> 8, tile = id & 255;
      W = p.Wfc + (size_t)l * 1048064; D = p.wfcT + (size_t)l * 1048576;
      K = 512; N = 2047; ldk = 512; n0 = (tile >> 3) * 64; k0 = (tile & 7) * 64;
    } else if (t < 9408) {
      int id = t - 6336; int l = id >> 8, tile = id & 255;
      W = p.Wpr + (size_t)l * 1046528 + 511; D = p.wprT + (size_t)l * 1048576;
      K = 2047; N = 511; ldk = 2048; n0 = (tile >> 5) * 64; k0 = (tile & 31) * 64;
    } else {
      int id = t - 9408;
      W = p.Wfin; D = p.wfinT; K = 512; N = 511; ldk = 512;
      n0 = (id >> 3) * 64; k0 = (id & 7) * 64;
    }
    trans_tile(W, D, K, N, ldk, n0, k0, SM);
  }
  for (int i = tt * 512 + tid; i < 2048 * 120; i += 256 * 512)
    p.ao[(size_t)(i / 120) * 640 + 520 + (i % 120)] = (f16)0.f;
  embed_row(xreg, myrow, p.tok, p.etab, p.ln1g, p.ln1b, p.actA, p.ssq);
  gbar2(p.bar, myxcc, Nx, NXCD);

  for (int li = 0; li < 12; li++) {
    const f16* wqkvT_l = p.wqkvT + (size_t)li * 786432;
    const f16* woT_l = p.woT + (size_t)li * 327680;
    const f16* wfcT_l = p.wfcT + (size_t)li * 1048576;
    const f16* wprT_l = p.wprT + (size_t)li * 1048576;
    const float* bq_l = p.bq + li * 512;
    const float* bk_l = p.bk + li * 512;
    const float* bv_l = p.bv + li * 512;
    const float* bo_l = p.bo + li * 511;
    const float* bfc_l = p.bfc + li * 2047;
    const float* bpr_l = p.bpr + li * 511;
    const float* w0_l = p.Wpr + (size_t)li * 1046528;

    for (int t = tt; t < 192; t += 256)
      gemm_task<1>(p.actA, wqkvT_l, 512, 512, t / 12, t % 12, 0, 8, nullptr,
                   bq_l, bk_l, bv_l, nullptr, p.qhat, p.khat, p.vT, 0, SM);
    gbar2(p.bar, myxcc, Nx, NXCD);
    if (wid < 4) {
      int T = wid * 16 + ((wid & 1) ? (15 - (tt >> 4)) : (tt >> 4));
      attn_task(T * 16 + (tt & 15), p.qhat, p.khat, p.vT, p.ao, SM + wid * 2816);
    }
    gbar2(p.bar, myxcc, Nx, NXCD);
    for (int t = tt; t < 128; t += 256) {
      int tm = t >> 3, tn = (t >> 1) & 3, tz = t & 1;
      gemm_task<0>(p.ao, woT_l, 640, 640, tm, tn, tz * 320, 5,
                   tz ? p.rawB : p.rawA, nullptr, nullptr, nullptr, nullptr,
                   nullptr, nullptr, nullptr, 0, SM);
    }
    gbar2(p.bar, myxcc, Nx, NXCD);
    resproj_row(xreg, myrow, p.rawA, p.rawB, nullptr, nullptr, 2, bo_l, p.rw1[li],
                p.ln2g + li * 511, p.ln2b + li * 511, p.actA, 1, p.ssq);
    gbar2(p.bar, myxcc, Nx, NXCD);
    for (int t = tt; t < 256; t += 256)
      gemm_task<2>(p.actA, wfcT_l, 512, 512, t >> 4, t & 15, 0, 8, nullptr,
                   bfc_l, nullptr, nullptr, p.ssq, p.fcact, nullptr, nullptr, 0, SM);
    gbar2(p.bar, myxcc, Nx, NXCD);
    for (int t = tt; t < 256; t += 256) {
      int tm = t >> 4, tn = (t >> 2) & 3, tz = t & 3;
      float* O = tz == 0 ? p.rawA : tz == 1 ? p.rawB : tz == 2 ? p.rawC : p.rawD;
      gemm_task<3>(p.fcact, wprT_l, 2048, 2048, tm, tn, tz * 512, 8, O,
                   w0_l, nullptr, nullptr, p.ssq, nullptr, nullptr, nullptr, tz == 0, SM);
    }
    gbar2(p.bar, myxcc, Nx, NXCD);
    const float* ng = (li < 11) ? p.ln1g + (li + 1) * 511 : p.ln1g;
    const float* nb = (li < 11) ? p.ln1b + (li + 1) * 511 : p.ln1b;
    resproj_row(xreg, myrow, p.rawA, p.rawB, p.rawC, p.rawD, 4, bpr_l, p.rw2[li],
                ng, nb, p.actA, (li < 11) ? 1 : 0, p.ssq);
    gbar2(p.bar, myxcc, Nx, NXCD);
  }

  for (int t = tt; t < 64; t += 256)
    gemm_task<0>(p.actA, p.wfinT, 512, 512, t >> 2, t & 3, 0, 8, p.rawA,
                 nullptr, nullptr, nullptr, nullptr, nullptr, nullptr, nullptr, 0, SM);
  gbar2(p.bar, myxcc, Nx, NXCD);
  final_row(myrow, p.rawA, p.bfin, p.lnfg, p.lnfb, p.out);
}

extern "C" void kernel_launch(void* const* d_in, const int* in_sizes, int n_in,
                              void* d_out, int out_size, void* d_ws, size_t ws_size,
                              hipStream_t stream) {
  (void)in_sizes; (void)n_in; (void)out_size; (void)ws_size;
  MP p;
  p.tok = (const int*)d_in[0];
  p.etab = (const float*)d_in[1];
  p.Wq = (const float*)d_in[2];  p.bq = (const float*)d_in[3];
  p.Wk = (const float*)d_in[4];  p.bk = (const float*)d_in[5];
  p.Wv = (const float*)d_in[6];  p.bv = (const float*)d_in[7];
  p.Wo = (const float*)d_in[8];  p.bo = (const float*)d_in[9];
  p.ln1g = (const float*)d_in[10]; p.ln1b = (const float*)d_in[11];
  p.ln2g = (const float*)d_in[12]; p.ln2b = (const float*)d_in[13];
  p.Wfc = (const float*)d_in[14]; p.bfc = (const float*)d_in[15];
  p.Wpr = (const float*)d_in[16]; p.bpr = (const float*)d_in[17];
  p.rw1 = (const float*)d_in[18]; p.rw2 = (const float*)d_in[19];
  p.Wfin = (const float*)d_in[20]; p.bfin = (const float*)d_in[21];
  p.lnfg = (const float*)d_in[22]; p.lnfb = (const float*)d_in[23];

  char* wsb = (char*)d_ws;
  size_t off = 0;
  auto alloc = [&](size_t bytes) -> char* {
    char* q = wsb + off;
    off = (off + bytes + 1023) & ~(size_t)1023;
    return q;
  };
  p.actA = (f16*)alloc(2048ull * 512 * 2);
  p.rawA = (float*)alloc(2048ull * 520 * 4);
  p.rawB = (float*)alloc(2048ull * 520 * 4);
  p.rawC = (float*)alloc(2048ull * 520 * 4);
  p.rawD = (float*)alloc(2048ull * 520 * 4);
  p.ssq = (float*)alloc(2048ull * 4);
  p.qhat = (f16*)alloc(16ull * 1024 * 88 * 2);
  p.khat = (f16*)alloc(16ull * 1024 * 88 * 2);
  p.vT = (f16*)alloc(16ull * 80 * 1024 * 2);
  p.ao = (f16*)alloc(2048ull * 640 * 2);
  p.fcact = (f16*)alloc(2048ull * 2048 * 2);
  p.wqkvT = (f16*)alloc(12ull * 786432 * 2);
  p.woT = (f16*)alloc(12ull * 327680 * 2);
  p.wfcT = (f16*)alloc(12ull * 1048576 * 2);
  p.wprT = (f16*)alloc(12ull * 1048576 * 2);
  p.wfinT = (f16*)alloc(512ull * 512 * 2);
  p.bar = (u32*)alloc(4096);
  p.out = (float*)d_out;

  hipMemsetAsync(p.bar, 0, 4096, stream);
  k_mega<<<256, 512, 0, stream>>>(p);
}